// Round 7
// baseline (535.215 us; speedup 1.0000x reference)
//
#include <hip/hip_runtime.h>
#include <hip/hip_bf16.h>
#include <stdint.h>
#include <math.h>

// ---------------------------------------------------------------------------
// MHA: x[8192,1024] (fp32 or bf16, detected) -> bf16 -> qkv GEMM (m97 gl16)
// -> causal flash attn (BK=64, barrier-free, uniform 33-iter tile pairs)
// -> proj + bias.
// ---------------------------------------------------------------------------

typedef __attribute__((ext_vector_type(8))) short short8;   // 8 x bf16 frag
typedef __attribute__((ext_vector_type(4))) float f32x4;    // C/D frag

#define LOG2E 1.44269504088896340736f

__device__ int g_isf32;   // 1 if inputs/outputs are fp32, 0 if bf16

__device__ __forceinline__ void gl16(const void* g, void* l) {
  __builtin_amdgcn_global_load_lds(
      (const __attribute__((address_space(1))) unsigned int*)g,
      (__attribute__((address_space(3))) unsigned int*)l, 16, 0, 0);
}

__device__ __forceinline__ short f2bf(float f) {
  __hip_bfloat16 h = __float2bfloat16(f);
  return *reinterpret_cast<short*>(&h);
}
__device__ __forceinline__ float bf2f(short s) {
  __hip_bfloat16 h = *reinterpret_cast<__hip_bfloat16*>(&s);
  return __bfloat162float(h);
}
__device__ __forceinline__ short8 pack8(f32x4 lo, f32x4 hi) {
  short8 r;
#pragma unroll
  for (int e = 0; e < 4; ++e) { r[e] = f2bf(lo[e]); r[4 + e] = f2bf(hi[e]); }
  return r;
}

// ---------------------------------------------------------------------------
// Dtype detection from w_qkv bit patterns (fp32 mantissa halves hit exponent
// 0xFF ~1/256; bf16 N(0,0.03) weights never do).
// ---------------------------------------------------------------------------
__global__ __launch_bounds__(256) void detect_dtype(const unsigned short* w) {
  __shared__ int cnt;
  if (threadIdx.x == 0) cnt = 0;
  __syncthreads();
  const unsigned short* p = w + (long)blockIdx.x * 49152;
  int c = 0;
  for (int i = threadIdx.x; i < 49152; i += 256)
    if (((p[i] >> 7) & 0xFF) == 0xFF) c++;
  atomicAdd(&cnt, c);
  __syncthreads();
  if (threadIdx.x == 0) g_isf32 = (cnt > 8) ? 1 : 0;
}

// ---------------------------------------------------------------------------
// x -> bf16 copy/convert (8 elems per thread)
// ---------------------------------------------------------------------------
__global__ __launch_bounds__(256) void cvt_x(const void* __restrict__ src,
                                             short* __restrict__ dst) {
  const long i = ((long)blockIdx.x * 256 + threadIdx.x) * 8;
  if (g_isf32) {
    const float* s = (const float*)src + i;
    *(short8*)(dst + i) = pack8(*(const f32x4*)s, *(const f32x4*)(s + 4));
  } else {
    *(short8*)(dst + i) = *(const short8*)((const short*)src + i);
  }
}

// ---------------------------------------------------------------------------
// gemm_bt: C = A[M,K]*Bt[N,K]^T. m97 structure: 128x128 tile, BK=32,
// global_load_lds 16B staging, 16x16x32 bf16 MFMA, 4 waves 2x2. A,Bt bf16.
// MODE 1: C(+bias), dtype per g_isf32. MODE 2: qkv split epilogue (bf16):
//   col<2048 -> qk[row*2048+col]; col>=2048 -> vt[bh][d][t] transposed.
// ---------------------------------------------------------------------------
template <int MODE>
__global__ __launch_bounds__(256) void gemm_bt(
    const short* __restrict__ A, const short* __restrict__ Bt,
    const void* __restrict__ bias, void* __restrict__ C,
    short* __restrict__ vt, int M, int N, int K)
{
  __shared__ __align__(16) short As[128 * 32];
  __shared__ __align__(16) short Bs[128 * 32];
  const int isf32 = g_isf32;
  const int tid  = threadIdx.x;
  const int lane = tid & 63;
  const int wave = tid >> 6;
  const int quad = lane >> 4;
  const int l16  = lane & 15;
  const int wm = (wave & 1) * 64;
  const int wn = (wave >> 1) * 64;
  const long m0 = (long)blockIdx.y * 128;
  const long n0 = (long)blockIdx.x * 128;

  f32x4 acc[4][4] = {};

  const int r4 = tid >> 2;   // row within 64-row half
  const int c4 = tid & 3;    // 16B chunk within 32-elem row
  const short* Ag = A  + (m0 + r4) * (long)K + c4 * 8;
  const short* Bg = Bt + (n0 + r4) * (long)K + c4 * 8;
  const long rowskip = (long)64 * K;

  for (int k0 = 0; k0 < K; k0 += 32) {
    __syncthreads();
    gl16(Ag + k0,           (char*)As + tid * 16);
    gl16(Ag + k0 + rowskip, (char*)As + 4096 + tid * 16);
    gl16(Bg + k0,           (char*)Bs + tid * 16);
    gl16(Bg + k0 + rowskip, (char*)Bs + 4096 + tid * 16);
    __syncthreads();
    short8 af[4], bfv[4];
#pragma unroll
    for (int i = 0; i < 4; ++i)
      af[i] = *(const short8*)&As[(wm + i * 16 + l16) * 32 + quad * 8];
#pragma unroll
    for (int j = 0; j < 4; ++j)
      bfv[j] = *(const short8*)&Bs[(wn + j * 16 + l16) * 32 + quad * 8];
#pragma unroll
    for (int i = 0; i < 4; ++i)
#pragma unroll
      for (int j = 0; j < 4; ++j)
        acc[i][j] = __builtin_amdgcn_mfma_f32_16x16x32_bf16(af[i], bfv[j], acc[i][j], 0, 0, 0);
  }

#pragma unroll
  for (int j = 0; j < 4; ++j) {
    const long col = n0 + wn + j * 16 + l16;
    float bv = 0.f;
    if (MODE == 1)
      bv = isf32 ? ((const float*)bias)[col] : bf2f(((const short*)bias)[col]);
#pragma unroll
    for (int i = 0; i < 4; ++i) {
      const long row0 = m0 + wm + i * 16 + quad * 4;
#pragma unroll
      for (int r = 0; r < 4; ++r) {
        const long row = row0 + r;
        const float val = acc[i][j][r] + bv;
        if (MODE == 2) {
          if (col < 2048) {
            ((short*)C)[row * 2048 + col] = f2bf(val);
          } else {
            const long b = row >> 11, t = row & 2047;
            const long hd = col - 2048;            // h*64 + d
            vt[((b * 16 + (hd >> 6)) * 64 + (hd & 63)) * 2048 + t] = f2bf(val);
          }
        } else {
          if (isf32) ((float*)C)[row * (long)N + col] = val;
          else       ((short*)C)[row * (long)N + col] = f2bf(val);
        }
      }
    }
  }
}

// ---------------------------------------------------------------------------
// 64x64 transpose + cast-to-bf16: dst[C,R] = (bf16)src[R,C]^T
// ---------------------------------------------------------------------------
__global__ __launch_bounds__(256) void transpose64(
    const void* __restrict__ src, short* __restrict__ dst, int R, int C)
{
  __shared__ __align__(16) short tile[64][72];
  const int isf32 = g_isf32;
  const int tid = threadIdx.x;
  const long r0 = (long)blockIdx.y * 64;
  const long c0 = (long)blockIdx.x * 64;
#pragma unroll
  for (int it = 0; it < 2; ++it) {
    int idx = it * 256 + tid;
    int rr = idx >> 3, ch = idx & 7;
    const long off = (r0 + rr) * C + c0 + ch * 8;
    short8 v;
    if (isf32) {
      const float* s = (const float*)src + off;
      v = pack8(*(const f32x4*)s, *(const f32x4*)(s + 4));
    } else {
      v = *(const short8*)((const short*)src + off);
    }
    *(short8*)&tile[rr][ch * 8] = v;
  }
  __syncthreads();
#pragma unroll
  for (int it = 0; it < 2; ++it) {
    int idx = it * 256 + tid;
    int cc = idx >> 3, ch = idx & 7;
    short8 v;
#pragma unroll
    for (int jj = 0; jj < 8; ++jj) v[jj] = tile[ch * 8 + jj][cc];
    *(short8*)&dst[(c0 + cc) * R + r0 + ch * 8] = v;
  }
}

// ---------------------------------------------------------------------------
// Flash attention (causal).  grid=(64 bh, 16); each block processes the
// UNIFORM tile pair {31-g, g} sequentially -> exactly 33 k-iterations per
// block (kills the causal tail; round-6 counter showed Occupancy 31%).
// 4 waves x 16 q-rows per 64-row tile, BK=64, barrier-free (Pw wave-private),
// per-lane l, diagonal upper-half skip.  Pw is f32 stride-68 (2-way banks).
// ---------------------------------------------------------------------------
__global__ __launch_bounds__(256) void attn_fwd(
    const short* __restrict__ qk, const short* __restrict__ vt,
    short* __restrict__ out)
{
  __shared__ __align__(16) float Pw[4][16][68];
  const int tid = threadIdx.x;
  const int lane = tid & 63, wave = tid >> 6;
  const int quad = lane >> 4, l16 = lane & 15;
  const int bh = blockIdx.x;
  const int b = bh >> 4, h = bh & 15;
  const short* kbase = qk + (long)b * 2048 * 2048 + 1024 + h * 64;
  const short* vbase = vt + (long)bh * 64 * 2048;
  const float sc = 0.125f * LOG2E;

  for (int tt = 0; tt < 2; ++tt) {
    const int jq = tt ? (int)blockIdx.y : 31 - (int)blockIdx.y;
    const int qbase = jq * 64 + wave * 16;
    const int qlast = qbase + 15;

    const short* qp = qk + ((long)(b * 2048 + qbase + l16)) * 2048 + h * 64 + quad * 8;
    const short8 aq0 = *(const short8*)qp;
    const short8 aq1 = *(const short8*)(qp + 32);

    f32x4 o[4] = {};
    float m_run[4], l_run[4];
#pragma unroll
    for (int r = 0; r < 4; ++r) { m_run[r] = -1e30f; l_run[r] = 0.f; }

    const int nk = jq + 1;                        // 64-wide k tiles

    for (int kt = 0; kt < nk; ++kt) {
      const int k0 = kt * 64;
      const bool h2 = (k0 + 32) <= qlast;         // wave-uniform: upper half live

      // S = Q K^T : 4 col-tiles (c), kdim 64 = 2 MFMA each
      f32x4 s[4];
#pragma unroll
      for (int c = 0; c < 4; ++c) {
        if (c < 2 || h2) {
          const short* kr = kbase + (long)(k0 + c * 16 + l16) * 2048 + quad * 8;
          short8 kf0 = *(const short8*)kr;
          short8 kf1 = *(const short8*)(kr + 32);
          f32x4 z = {};
          z = __builtin_amdgcn_mfma_f32_16x16x32_bf16(aq0, kf0, z, 0, 0, 0);
          z = __builtin_amdgcn_mfma_f32_16x16x32_bf16(aq1, kf1, z, 0, 0, 0);
          s[c] = z;
        }
      }

      // scale + causal mask (C-layout: q = qbase+quad*4+r, k = k0+c*16+l16)
      float t[4][4];
#pragma unroll
      for (int c = 0; c < 4; ++c)
        if (c < 2 || h2)
#pragma unroll
          for (int r = 0; r < 4; ++r) {
            const int qg = qbase + quad * 4 + r;
            t[c][r] = (k0 + c * 16 + l16 > qg) ? -1e30f : s[c][r] * sc;
          }

      // row max: combine tiles, then 16-lane butterfly
      float mx[4];
#pragma unroll
      for (int r = 0; r < 4; ++r) {
        mx[r] = fmaxf(t[0][r], t[1][r]);
        if (h2) mx[r] = fmaxf(mx[r], fmaxf(t[2][r], t[3][r]));
      }
#pragma unroll
      for (int off = 1; off < 16; off <<= 1)
#pragma unroll
        for (int r = 0; r < 4; ++r) mx[r] = fmaxf(mx[r], __shfl_xor(mx[r], off, 64));

      // online update; l stays per-lane (alpha is row-uniform)
      float alpha[4], p[4][4];
#pragma unroll
      for (int r = 0; r < 4; ++r) {
        const float mn = fmaxf(m_run[r], mx[r]);
        alpha[r] = exp2f(m_run[r] - mn);
        m_run[r] = mn;
        float ps = 0.f;
#pragma unroll
        for (int c = 0; c < 4; ++c)
          if (c < 2 || h2) { p[c][r] = exp2f(t[c][r] - mn); ps += p[c][r]; }
        l_run[r] = l_run[r] * alpha[r] + ps;
      }
#pragma unroll
      for (int i = 0; i < 4; ++i)
#pragma unroll
        for (int r = 0; r < 4; ++r) o[i][r] *= alpha[r];

      // P: C-layout -> A-layout via wave-private f32 LDS (no barriers)
#pragma unroll
      for (int c = 0; c < 4; ++c)
        if (c < 2 || h2)
#pragma unroll
          for (int r = 0; r < 4; ++r)
            Pw[wave][quad * 4 + r][c * 16 + l16] = p[c][r];

      // O += P V : chunk0 (k in [k0,k0+32))
      {
        f32x4 pa = *(const f32x4*)&Pw[wave][l16][quad * 8];
        f32x4 pb = *(const f32x4*)&Pw[wave][l16][quad * 8 + 4];
        short8 pf0 = pack8(pa, pb);
#pragma unroll
        for (int i = 0; i < 4; ++i) {
          const short* vr = vbase + (long)(i * 16 + l16) * 2048 + k0 + quad * 8;
          o[i] = __builtin_amdgcn_mfma_f32_16x16x32_bf16(pf0, *(const short8*)vr, o[i], 0, 0, 0);
        }
      }
      if (h2) {
        f32x4 pa = *(const f32x4*)&Pw[wave][l16][32 + quad * 8];
        f32x4 pb = *(const f32x4*)&Pw[wave][l16][32 + quad * 8 + 4];
        short8 pf1 = pack8(pa, pb);
#pragma unroll
        for (int i = 0; i < 4; ++i) {
          const short* vr = vbase + (long)(i * 16 + l16) * 2048 + k0 + 32 + quad * 8;
          o[i] = __builtin_amdgcn_mfma_f32_16x16x32_bf16(pf1, *(const short8*)vr, o[i], 0, 0, 0);
        }
      }
    }

    // final row-sum of per-lane l, then normalize + store
#pragma unroll
    for (int off = 1; off < 16; off <<= 1)
#pragma unroll
      for (int r = 0; r < 4; ++r) l_run[r] += __shfl_xor(l_run[r], off, 64);
    float inv[4];
#pragma unroll
    for (int r = 0; r < 4; ++r) inv[r] = 1.0f / l_run[r];
    short* op = out + ((long)(b * 2048 + qbase + quad * 4)) * 1024 + h * 64;
#pragma unroll
    for (int i = 0; i < 4; ++i)
#pragma unroll
      for (int r = 0; r < 4; ++r)
        op[(long)r * 1024 + i * 16 + l16] = f2bf(o[i][r] * inv[r]);
  }
}

// ---------------------------------------------------------------------------
// plan-B epilogue copy: projout (qk region) -> d_out
// ---------------------------------------------------------------------------
__global__ __launch_bounds__(256) void copy_out(const void* __restrict__ src,
                                                void* __restrict__ dst)
{
  const long n16 = g_isf32 ? 2097152L : 1048576L;   // uint4 chunks
  const uint4* s = (const uint4*)src;
  uint4* d = (uint4*)dst;
  for (long i = (long)blockIdx.x * 256 + threadIdx.x; i < n16;
       i += (long)gridDim.x * 256)
    d[i] = s[i];
}

// ---------------------------------------------------------------------------
extern "C" void kernel_launch(void* const* d_in, const int* in_sizes, int n_in,
                              void* d_out, int out_size, void* d_ws, size_t ws_size,
                              hipStream_t stream)
{
  const void* x      = d_in[0];   // [8192,1024]  fp32 or bf16
  const void* w_qkv  = d_in[1];   // [1024,3072]
  const void* w_proj = d_in[2];   // [1024,1024]
  const void* b_proj = d_in[3];   // [1024]

  short* ws = (short*)d_ws;
  const bool planA = ws_size >= 67108864ULL;   // 64 MiB

  short* qk  = ws;                 // [8192,2048] bf16    = 32 MiB
  short* vtp = ws + 16777216L;     // [64][64][2048] bf16 = 16 MiB

  short *wqkvT, *attnb, *wprojT, *xbf;
  void*  projC;
  if (planA) {
    attnb  = ws + 25165824L;       // 16 MiB, [48,64) MiB of ws
    wqkvT  = attnb;                // aliased; dead once qkv GEMM reads done
    wprojT = qk;                   // aliased; written after attn_fwd
    xbf    = (short*)d_out;        // 16 MiB in dead d_out; dead after qkv GEMM
    projC  = d_out;
  } else {
    wqkvT  = (short*)d_out;        // d_out dead until the end
    xbf    = (short*)d_out + 3145728L;
    attnb  = (short*)d_out;        // overwrites wqkvT/xbf after both dead
    wprojT = vtp;                  // vtp dead after attn_fwd
    projC  = qk;                   // qk dead after attn_fwd (32 MiB fits fp32)
  }

  // 0. detect dtype; convert x to bf16
  detect_dtype<<<64, 256, 0, stream>>>((const unsigned short*)w_qkv);
  cvt_x<<<4096, 256, 0, stream>>>(x, xbf);
  // 1. W_qkv^T (cast to bf16)
  transpose64<<<dim3(3072 / 64, 1024 / 64), 256, 0, stream>>>(w_qkv, wqkvT, 1024, 3072);
  // 2. qkv GEMM, split epilogue (Q,K row-major bf16; V transposed into vtp)
  gemm_bt<2><<<dim3(3072 / 128, 8192 / 128), 256, 0, stream>>>(
      xbf, wqkvT, nullptr, qk, vtp, 8192, 3072, 1024);
  // 3. flash attention (uniform tile pairs)
  attn_fwd<<<dim3(64, 16), 256, 0, stream>>>(qk, vtp, attnb);
  // 4. W_proj^T (cast to bf16)
  transpose64<<<dim3(1024 / 64, 1024 / 64), 256, 0, stream>>>(w_proj, wprojT, 1024, 1024);
  // 5. output projection + bias
  gemm_bt<1><<<dim3(1024 / 128, 8192 / 128), 256, 0, stream>>>(
      attnb, wprojT, b_proj, projC, nullptr, 8192, 1024, 1024);
  // 6. plan-B: move result into d_out
  if (!planA)
    copy_out<<<2048, 256, 0, stream>>>(projC, d_out);
}

// Round 8
// 371.668 us; speedup vs baseline: 1.4400x; 1.4400x over previous
//
#include <hip/hip_runtime.h>
#include <hip/hip_bf16.h>
#include <stdint.h>
#include <math.h>

// ---------------------------------------------------------------------------
// MHA: x[8192,1024] (fp32 or bf16, detected) -> bf16 -> qkv GEMM (m97 gl16)
// -> causal flash attn (LDS-staged K/V shared by 4 waves, BK=64)
// -> proj + bias.
// ---------------------------------------------------------------------------

typedef __attribute__((ext_vector_type(8))) short short8;   // 8 x bf16 frag
typedef __attribute__((ext_vector_type(4))) float f32x4;    // C/D frag

#define LOG2E 1.44269504088896340736f

__device__ int g_isf32;   // 1 if inputs/outputs are fp32, 0 if bf16

__device__ __forceinline__ void gl16(const void* g, void* l) {
  __builtin_amdgcn_global_load_lds(
      (const __attribute__((address_space(1))) unsigned int*)g,
      (__attribute__((address_space(3))) unsigned int*)l, 16, 0, 0);
}

__device__ __forceinline__ short f2bf(float f) {
  __hip_bfloat16 h = __float2bfloat16(f);
  return *reinterpret_cast<short*>(&h);
}
__device__ __forceinline__ float bf2f(short s) {
  __hip_bfloat16 h = *reinterpret_cast<__hip_bfloat16*>(&s);
  return __bfloat162float(h);
}
__device__ __forceinline__ short8 pack8(f32x4 lo, f32x4 hi) {
  short8 r;
#pragma unroll
  for (int e = 0; e < 4; ++e) { r[e] = f2bf(lo[e]); r[4 + e] = f2bf(hi[e]); }
  return r;
}

// ---------------------------------------------------------------------------
// Dtype detection from w_qkv bit patterns (fp32 mantissa halves hit exponent
// 0xFF ~1/256; bf16 N(0,0.03) weights never do).
// ---------------------------------------------------------------------------
__global__ __launch_bounds__(256) void detect_dtype(const unsigned short* w) {
  __shared__ int cnt;
  if (threadIdx.x == 0) cnt = 0;
  __syncthreads();
  const unsigned short* p = w + (long)blockIdx.x * 49152;
  int c = 0;
  for (int i = threadIdx.x; i < 49152; i += 256)
    if (((p[i] >> 7) & 0xFF) == 0xFF) c++;
  atomicAdd(&cnt, c);
  __syncthreads();
  if (threadIdx.x == 0) g_isf32 = (cnt > 8) ? 1 : 0;
}

// ---------------------------------------------------------------------------
// x -> bf16 copy/convert (8 elems per thread)
// ---------------------------------------------------------------------------
__global__ __launch_bounds__(256) void cvt_x(const void* __restrict__ src,
                                             short* __restrict__ dst) {
  const long i = ((long)blockIdx.x * 256 + threadIdx.x) * 8;
  if (g_isf32) {
    const float* s = (const float*)src + i;
    *(short8*)(dst + i) = pack8(*(const f32x4*)s, *(const f32x4*)(s + 4));
  } else {
    *(short8*)(dst + i) = *(const short8*)((const short*)src + i);
  }
}

// ---------------------------------------------------------------------------
// gemm_bt: C = A[M,K]*Bt[N,K]^T. m97 structure: 128x128 tile, BK=32,
// global_load_lds 16B staging, 16x16x32 bf16 MFMA, 4 waves 2x2. A,Bt bf16.
// MODE 1: C(+bias), dtype per g_isf32. MODE 2: qkv split epilogue (bf16):
//   col<2048 -> qk[row*2048+col]; col>=2048 -> vt[bh][d][t] transposed.
// ---------------------------------------------------------------------------
template <int MODE>
__global__ __launch_bounds__(256) void gemm_bt(
    const short* __restrict__ A, const short* __restrict__ Bt,
    const void* __restrict__ bias, void* __restrict__ C,
    short* __restrict__ vt, int M, int N, int K)
{
  __shared__ __align__(16) short As[128 * 32];
  __shared__ __align__(16) short Bs[128 * 32];
  const int isf32 = g_isf32;
  const int tid  = threadIdx.x;
  const int lane = tid & 63;
  const int wave = tid >> 6;
  const int quad = lane >> 4;
  const int l16  = lane & 15;
  const int wm = (wave & 1) * 64;
  const int wn = (wave >> 1) * 64;
  const long m0 = (long)blockIdx.y * 128;
  const long n0 = (long)blockIdx.x * 128;

  f32x4 acc[4][4] = {};

  const int r4 = tid >> 2;   // row within 64-row half
  const int c4 = tid & 3;    // 16B chunk within 32-elem row
  const short* Ag = A  + (m0 + r4) * (long)K + c4 * 8;
  const short* Bg = Bt + (n0 + r4) * (long)K + c4 * 8;
  const long rowskip = (long)64 * K;

  for (int k0 = 0; k0 < K; k0 += 32) {
    __syncthreads();
    gl16(Ag + k0,           (char*)As + tid * 16);
    gl16(Ag + k0 + rowskip, (char*)As + 4096 + tid * 16);
    gl16(Bg + k0,           (char*)Bs + tid * 16);
    gl16(Bg + k0 + rowskip, (char*)Bs + 4096 + tid * 16);
    __syncthreads();
    short8 af[4], bfv[4];
#pragma unroll
    for (int i = 0; i < 4; ++i)
      af[i] = *(const short8*)&As[(wm + i * 16 + l16) * 32 + quad * 8];
#pragma unroll
    for (int j = 0; j < 4; ++j)
      bfv[j] = *(const short8*)&Bs[(wn + j * 16 + l16) * 32 + quad * 8];
#pragma unroll
    for (int i = 0; i < 4; ++i)
#pragma unroll
      for (int j = 0; j < 4; ++j)
        acc[i][j] = __builtin_amdgcn_mfma_f32_16x16x32_bf16(af[i], bfv[j], acc[i][j], 0, 0, 0);
  }

#pragma unroll
  for (int j = 0; j < 4; ++j) {
    const long col = n0 + wn + j * 16 + l16;
    float bv = 0.f;
    if (MODE == 1)
      bv = isf32 ? ((const float*)bias)[col] : bf2f(((const short*)bias)[col]);
#pragma unroll
    for (int i = 0; i < 4; ++i) {
      const long row0 = m0 + wm + i * 16 + quad * 4;
#pragma unroll
      for (int r = 0; r < 4; ++r) {
        const long row = row0 + r;
        const float val = acc[i][j][r] + bv;
        if (MODE == 2) {
          if (col < 2048) {
            ((short*)C)[row * 2048 + col] = f2bf(val);
          } else {
            const long b = row >> 11, t = row & 2047;
            const long hd = col - 2048;            // h*64 + d
            vt[((b * 16 + (hd >> 6)) * 64 + (hd & 63)) * 2048 + t] = f2bf(val);
          }
        } else {
          if (isf32) ((float*)C)[row * (long)N + col] = val;
          else       ((short*)C)[row * (long)N + col] = f2bf(val);
        }
      }
    }
  }
}

// ---------------------------------------------------------------------------
// 64x64 transpose + cast-to-bf16: dst[C,R] = (bf16)src[R,C]^T
// ---------------------------------------------------------------------------
__global__ __launch_bounds__(256) void transpose64(
    const void* __restrict__ src, short* __restrict__ dst, int R, int C)
{
  __shared__ __align__(16) short tile[64][72];
  const int isf32 = g_isf32;
  const int tid = threadIdx.x;
  const long r0 = (long)blockIdx.y * 64;
  const long c0 = (long)blockIdx.x * 64;
#pragma unroll
  for (int it = 0; it < 2; ++it) {
    int idx = it * 256 + tid;
    int rr = idx >> 3, ch = idx & 7;
    const long off = (r0 + rr) * C + c0 + ch * 8;
    short8 v;
    if (isf32) {
      const float* s = (const float*)src + off;
      v = pack8(*(const f32x4*)s, *(const f32x4*)(s + 4));
    } else {
      v = *(const short8*)((const short*)src + off);
    }
    *(short8*)&tile[rr][ch * 8] = v;
  }
  __syncthreads();
#pragma unroll
  for (int it = 0; it < 2; ++it) {
    int idx = it * 256 + tid;
    int cc = idx >> 3, ch = idx & 7;
    short8 v;
#pragma unroll
    for (int jj = 0; jj < 8; ++jj) v[jj] = tile[ch * 8 + jj][cc];
    *(short8*)&dst[(c0 + cc) * R + r0 + ch * 8] = v;
  }
}

// ---------------------------------------------------------------------------
// Flash attention (causal).  grid=(64 bh, 32 q-tiles) big-first.  Block =
// 4 waves x 16 q-rows.  K tile (split d-halves) and V^T tile (split k-halves)
// staged to LDS via global_load_lds ONCE per block, shared by all 4 waves
// (round-7 PMC showed per-wave direct loads latency-bound: MfmaUtil 5%,
// VALUBusy 30%, 60% all-wave stall).  64B LDS rows = GEMM-identical 2-way
// (free) frag reads.  Pw bf16 stride-76 (quads on distinct bank octets).
// Barrier-free softmax section; per-wave diagonal upper-half skip (no
// barriers inside, counts stay uniform).
// ---------------------------------------------------------------------------
__global__ __launch_bounds__(256) void attn_fwd(
    const short* __restrict__ qk, const short* __restrict__ vt,
    short* __restrict__ out)
{
  __shared__ __align__(16) short Ks[2][64][32];   // [d-half][k-row][d%32]
  __shared__ __align__(16) short Vs[2][64][32];   // [k-half][d][k%32]
  __shared__ __align__(16) short Pw[4][16][76];   // wave-private P, bf16
  const int tid = threadIdx.x;
  const int lane = tid & 63, wave = tid >> 6;
  const int quad = lane >> 4, l16 = lane & 15;
  const int bh = blockIdx.x;
  const int b = bh >> 4, h = bh & 15;
  const int jq = (int)gridDim.y - 1 - (int)blockIdx.y;  // big-work blocks first
  const int qbase = jq * 64 + wave * 16;
  const int qlast = qbase + 15;

  // Q A-frags (rows qbase+l16, two 32-wide d slices)
  const short* qp = qk + ((long)(b * 2048 + qbase + l16)) * 2048 + h * 64 + quad * 8;
  const short8 aq0 = *(const short8*)qp;
  const short8 aq1 = *(const short8*)(qp + 32);

  // staging sources: row sr (k-row for K, d for V), 16B chunk sc_
  const int sr = tid >> 2, sc_ = tid & 3;
  const short* kg = qk + (long)b * 2048 * 2048 + 1024 + h * 64 + (long)sr * 2048 + sc_ * 8;
  const short* vg = vt + ((long)bh * 64 + sr) * 2048 + sc_ * 8;

  f32x4 o[4] = {};
  float m_run[4], l_run[4];
#pragma unroll
  for (int r = 0; r < 4; ++r) { m_run[r] = -1e30f; l_run[r] = 0.f; }

  const int nk = jq + 1;                        // 64-wide k tiles
  const float sc = 0.125f * LOG2E;

  for (int kt = 0; kt < nk; ++kt) {
    const int k0 = kt * 64;
    const bool h2 = (k0 + 32) <= qlast;         // wave-uniform: upper half live

    __syncthreads();                            // prev-tile readers done
    gl16(kg + (long)k0 * 2048,      (char*)Ks + tid * 16);         // d 0-31
    gl16(kg + (long)k0 * 2048 + 32, (char*)Ks + 4096 + tid * 16);  // d 32-63
    gl16(vg + k0,                   (char*)Vs + tid * 16);         // k 0-31
    gl16(vg + k0 + 32,              (char*)Vs + 4096 + tid * 16);  // k 32-63
    __syncthreads();                            // staging visible

    // S = Q K^T : 4 col-tiles (c), kdim 64 = 2 MFMA each, frags from LDS
    f32x4 s[4];
#pragma unroll
    for (int c = 0; c < 4; ++c) {
      if (c < 2 || h2) {
        short8 kf0 = *(const short8*)&Ks[0][c * 16 + l16][quad * 8];
        short8 kf1 = *(const short8*)&Ks[1][c * 16 + l16][quad * 8];
        f32x4 z = {};
        z = __builtin_amdgcn_mfma_f32_16x16x32_bf16(aq0, kf0, z, 0, 0, 0);
        z = __builtin_amdgcn_mfma_f32_16x16x32_bf16(aq1, kf1, z, 0, 0, 0);
        s[c] = z;
      }
    }

    // scale + causal mask (C-layout: q = qbase+quad*4+r, k = k0+c*16+l16)
    float t[4][4];
#pragma unroll
    for (int c = 0; c < 4; ++c)
      if (c < 2 || h2)
#pragma unroll
        for (int r = 0; r < 4; ++r) {
          const int qg = qbase + quad * 4 + r;
          t[c][r] = (k0 + c * 16 + l16 > qg) ? -1e30f : s[c][r] * sc;
        }

    // row max: combine tiles, then 16-lane butterfly
    float mx[4];
#pragma unroll
    for (int r = 0; r < 4; ++r) {
      mx[r] = fmaxf(t[0][r], t[1][r]);
      if (h2) mx[r] = fmaxf(mx[r], fmaxf(t[2][r], t[3][r]));
    }
#pragma unroll
    for (int off = 1; off < 16; off <<= 1)
#pragma unroll
      for (int r = 0; r < 4; ++r) mx[r] = fmaxf(mx[r], __shfl_xor(mx[r], off, 64));

    // online update; l stays per-lane (alpha is row-uniform)
    float alpha[4], p[4][4];
#pragma unroll
    for (int r = 0; r < 4; ++r) {
      const float mn = fmaxf(m_run[r], mx[r]);
      alpha[r] = exp2f(m_run[r] - mn);
      m_run[r] = mn;
      float ps = 0.f;
#pragma unroll
      for (int c = 0; c < 4; ++c)
        if (c < 2 || h2) { p[c][r] = exp2f(t[c][r] - mn); ps += p[c][r]; }
      l_run[r] = l_run[r] * alpha[r] + ps;
    }
#pragma unroll
    for (int i = 0; i < 4; ++i)
#pragma unroll
      for (int r = 0; r < 4; ++r) o[i][r] *= alpha[r];

    // P: C-layout -> bf16 A-layout via wave-private LDS (no barrier needed)
#pragma unroll
    for (int c = 0; c < 4; ++c)
      if (c < 2 || h2)
#pragma unroll
        for (int r = 0; r < 4; ++r)
          Pw[wave][quad * 4 + r][c * 16 + l16] = f2bf(p[c][r]);

    // O += P V : frags from LDS
    {
      short8 pf0 = *(const short8*)&Pw[wave][l16][quad * 8];
#pragma unroll
      for (int i = 0; i < 4; ++i) {
        short8 vf = *(const short8*)&Vs[0][i * 16 + l16][quad * 8];
        o[i] = __builtin_amdgcn_mfma_f32_16x16x32_bf16(pf0, vf, o[i], 0, 0, 0);
      }
    }
    if (h2) {
      short8 pf1 = *(const short8*)&Pw[wave][l16][32 + quad * 8];
#pragma unroll
      for (int i = 0; i < 4; ++i) {
        short8 vf = *(const short8*)&Vs[1][i * 16 + l16][quad * 8];
        o[i] = __builtin_amdgcn_mfma_f32_16x16x32_bf16(pf1, vf, o[i], 0, 0, 0);
      }
    }
  }

  // final row-sum of per-lane l, then normalize + store
#pragma unroll
  for (int off = 1; off < 16; off <<= 1)
#pragma unroll
    for (int r = 0; r < 4; ++r) l_run[r] += __shfl_xor(l_run[r], off, 64);
  float inv[4];
#pragma unroll
  for (int r = 0; r < 4; ++r) inv[r] = 1.0f / l_run[r];
  short* op = out + ((long)(b * 2048 + qbase + quad * 4)) * 1024 + h * 64;
#pragma unroll
  for (int i = 0; i < 4; ++i)
#pragma unroll
    for (int r = 0; r < 4; ++r)
      op[(long)r * 1024 + i * 16 + l16] = f2bf(o[i][r] * inv[r]);
}

// ---------------------------------------------------------------------------
// plan-B epilogue copy: projout (qk region) -> d_out
// ---------------------------------------------------------------------------
__global__ __launch_bounds__(256) void copy_out(const void* __restrict__ src,
                                                void* __restrict__ dst)
{
  const long n16 = g_isf32 ? 2097152L : 1048576L;   // uint4 chunks
  const uint4* s = (const uint4*)src;
  uint4* d = (uint4*)dst;
  for (long i = (long)blockIdx.x * 256 + threadIdx.x; i < n16;
       i += (long)gridDim.x * 256)
    d[i] = s[i];
}

// ---------------------------------------------------------------------------
extern "C" void kernel_launch(void* const* d_in, const int* in_sizes, int n_in,
                              void* d_out, int out_size, void* d_ws, size_t ws_size,
                              hipStream_t stream)
{
  const void* x      = d_in[0];   // [8192,1024]  fp32 or bf16
  const void* w_qkv  = d_in[1];   // [1024,3072]
  const void* w_proj = d_in[2];   // [1024,1024]
  const void* b_proj = d_in[3];   // [1024]

  short* ws = (short*)d_ws;
  const bool planA = ws_size >= 67108864ULL;   // 64 MiB

  short* qk  = ws;                 // [8192,2048] bf16    = 32 MiB
  short* vtp = ws + 16777216L;     // [64][64][2048] bf16 = 16 MiB

  short *wqkvT, *attnb, *wprojT, *xbf;
  void*  projC;
  if (planA) {
    attnb  = ws + 25165824L;       // 16 MiB, [48,64) MiB of ws
    wqkvT  = attnb;                // aliased; dead once qkv GEMM reads done
    wprojT = qk;                   // aliased; written after attn_fwd
    xbf    = (short*)d_out;        // 16 MiB in dead d_out; dead after qkv GEMM
    projC  = d_out;
  } else {
    wqkvT  = (short*)d_out;        // d_out dead until the end
    xbf    = (short*)d_out + 3145728L;
    attnb  = (short*)d_out;        // overwrites wqkvT/xbf after both dead
    wprojT = vtp;                  // vtp dead after attn_fwd
    projC  = qk;                   // qk dead after attn_fwd (32 MiB fits fp32)
  }

  // 0. detect dtype; convert x to bf16
  detect_dtype<<<64, 256, 0, stream>>>((const unsigned short*)w_qkv);
  cvt_x<<<4096, 256, 0, stream>>>(x, xbf);
  // 1. W_qkv^T (cast to bf16)
  transpose64<<<dim3(3072 / 64, 1024 / 64), 256, 0, stream>>>(w_qkv, wqkvT, 1024, 3072);
  // 2. qkv GEMM, split epilogue (Q,K row-major bf16; V transposed into vtp)
  gemm_bt<2><<<dim3(3072 / 128, 8192 / 128), 256, 0, stream>>>(
      xbf, wqkvT, nullptr, qk, vtp, 8192, 3072, 1024);
  // 3. flash attention (LDS-staged K/V)
  attn_fwd<<<dim3(64, 32), 256, 0, stream>>>(qk, vtp, attnb);
  // 4. W_proj^T (cast to bf16)
  transpose64<<<dim3(1024 / 64, 1024 / 64), 256, 0, stream>>>(w_proj, wprojT, 1024, 1024);
  // 5. output projection + bias
  gemm_bt<1><<<dim3(1024 / 128, 8192 / 128), 256, 0, stream>>>(
      attnb, wprojT, b_proj, projC, nullptr, 8192, 1024, 1024);
  // 6. plan-B: move result into d_out
  if (!planA)
    copy_out<<<2048, 256, 0, stream>>>(projC, d_out);
}